// Round 4
// baseline (349.548 us; speedup 1.0000x reference)
//
#include <hip/hip_runtime.h>
#include <stdint.h>

typedef short short8 __attribute__((ext_vector_type(8)));
typedef float f32x4 __attribute__((ext_vector_type(4)));

#define DDIM 256
#define NROWS 16384
#define KCB 8192
#define KSPLIT 4
#define KC 2048
#define ND 4194304

// async global -> LDS, 16 bytes per lane (dest = wave-uniform base + lane*16)
__device__ __forceinline__ void gll16(const void* g, void* l) {
    __builtin_amdgcn_global_load_lds(
        (const __attribute__((address_space(1))) unsigned int*)g,
        (__attribute__((address_space(3))) unsigned int*)l, 16, 0, 0);
}

// ---------------- bf16 RNE helpers ----------------
__device__ __forceinline__ unsigned short bf16_rne(float x) {
    unsigned u = __float_as_uint(x);
    unsigned r = (u + 0x7FFFu + ((u >> 16) & 1u)) >> 16;
    return (unsigned short)r;
}

// ---------------- split fp32 -> bf16 hi + lo ----------------
__global__ void k_split(const float* __restrict__ src, unsigned short* __restrict__ hi,
                        unsigned short* __restrict__ lo) {
    const int i = blockIdx.x * blockDim.x + threadIdx.x;
    float4 v = reinterpret_cast<const float4*>(src)[i];
    ushort4 h, l;
    h.x = bf16_rne(v.x); l.x = bf16_rne(v.x - __uint_as_float((unsigned)h.x << 16));
    h.y = bf16_rne(v.y); l.y = bf16_rne(v.y - __uint_as_float((unsigned)h.y << 16));
    h.z = bf16_rne(v.z); l.z = bf16_rne(v.z - __uint_as_float((unsigned)h.z << 16));
    h.w = bf16_rne(v.w); l.w = bf16_rne(v.w - __uint_as_float((unsigned)h.w << 16));
    reinterpret_cast<ushort4*>(hi)[i] = h;
    reinterpret_cast<ushort4*>(lo)[i] = l;
}

// ---------------- codebook norms (fp32 exact) ----------------
__global__ void k_norms(const float* __restrict__ cb, float* __restrict__ norms) {
    const int wave = threadIdx.x >> 6, lane = threadIdx.x & 63;
    const int row = blockIdx.x * 4 + wave;
    float4 v = *reinterpret_cast<const float4*>(cb + (size_t)row * DDIM + lane * 4);
    float s = v.x * v.x + v.y * v.y + v.z * v.z + v.w * v.w;
#pragma unroll
    for (int off = 32; off > 0; off >>= 1) s += __shfl_xor(s, off, 64);
    if (lane == 0) norms[row] = s;
}

// ---------------- MFMA score + top-2 argmin ----------------
// approx score(n,k) = ||e_k||^2 - 2*(zh.eh + zh.el + zl.eh)
__launch_bounds__(256, 2)
__global__ void k_score(const unsigned short* __restrict__ zh, const unsigned short* __restrict__ zl,
                        const unsigned short* __restrict__ eh, const unsigned short* __restrict__ el,
                        const float* __restrict__ norms,
                        float* __restrict__ cand_val, int* __restrict__ cand_idx) {
    __shared__ char smem[65536];   // 2 buffers x {Ah,Al,Bh,Bl} x [128 rows][32 d] bf16

    const int rb = blockIdx.x;     // row block 0..127
    const int ks = blockIdx.y;     // codebook split 0..3
    const int t = threadIdx.x;
    const int w = t >> 6, lane = t & 63;
    const int wr = w >> 1, wc = w & 1;       // wave quadrant
    const int l15 = lane & 15, l4 = lane >> 4;

    // staging mapping: thread t -> rows {t>>2, (t>>2)+64}, 16B chunk skg=t&3
    // LDS dest offset within an array = t*16 (linear in t => global_load_lds-compatible)
    const int srow = t >> 2, skg = t & 3;
    const int t16 = t * 16;
    const size_t abase = ((size_t)(rb * 128 + srow)) * DDIM + skg * 8;

    f32x4 acc[4][4];
    float v1[16], v2[16];
    int i1[16], i2[16];
#pragma unroll
    for (int q = 0; q < 16; ++q) { v1[q] = 3.4e38f; v2[q] = 3.4e38f; i1[q] = 0; i2[q] = 0; }

    // ---- prologue: stage step 0 (ct=0, dc=0) into buffer 0 (async) ----
    {
        const size_t bo = ((size_t)(ks * KC + srow)) * DDIM + skg * 8;
        char* buf = smem;
        gll16(zh + abase,                      buf + 0     + t16);
        gll16(zh + abase + (size_t)64 * DDIM,  buf + 0     + t16 + 4096);
        gll16(zl + abase,                      buf + 8192  + t16);
        gll16(zl + abase + (size_t)64 * DDIM,  buf + 8192  + t16 + 4096);
        gll16(eh + bo,                         buf + 16384 + t16);
        gll16(eh + bo + (size_t)64 * DDIM,     buf + 16384 + t16 + 4096);
        gll16(el + bo,                         buf + 24576 + t16);
        gll16(el + bo + (size_t)64 * DDIM,     buf + 24576 + t16 + 4096);
    }
    __syncthreads();   // drains vmcnt(0): buffer 0 ready

    for (int step = 0; step < 128; ++step) {
        const int p = step & 1;
        const int ct = step >> 3, dc = step & 7;
        if (dc == 0) {
#pragma unroll
            for (int fm = 0; fm < 4; ++fm)
#pragma unroll
                for (int fn = 0; fn < 4; ++fn) acc[fm][fn] = (f32x4){0.f, 0.f, 0.f, 0.f};
        }
        // issue async loads for next step into other buffer (overlaps with compute below)
        if (step + 1 < 128) {
            const int ct1 = (step + 1) >> 3, dc1 = (step + 1) & 7;
            const size_t ao = abase + dc1 * 32;
            const size_t bo = ((size_t)(ks * KC + ct1 * 128 + srow)) * DDIM + dc1 * 32 + skg * 8;
            char* buf = smem + (p ^ 1) * 32768;
            gll16(zh + ao,                     buf + 0     + t16);
            gll16(zh + ao + (size_t)64 * DDIM, buf + 0     + t16 + 4096);
            gll16(zl + ao,                     buf + 8192  + t16);
            gll16(zl + ao + (size_t)64 * DDIM, buf + 8192  + t16 + 4096);
            gll16(eh + bo,                     buf + 16384 + t16);
            gll16(eh + bo + (size_t)64 * DDIM, buf + 16384 + t16 + 4096);
            gll16(el + bo,                     buf + 24576 + t16);
            gll16(el + bo + (size_t)64 * DDIM, buf + 24576 + t16 + 4096);
        }
        // compute on current buffer
        {
            const char* cbuf = smem + p * 32768;
            short8 a_h[4], a_l[4];
#pragma unroll
            for (int fm = 0; fm < 4; ++fm) {
                const int ro = (wr * 64 + fm * 16 + l15) * 64 + l4 * 16;
                a_h[fm] = *reinterpret_cast<const short8*>(cbuf + ro);
                a_l[fm] = *reinterpret_cast<const short8*>(cbuf + 8192 + ro);
            }
#pragma unroll
            for (int fn = 0; fn < 4; ++fn) {
                const int co = (wc * 64 + fn * 16 + l15) * 64 + l4 * 16;
                short8 b_h = *reinterpret_cast<const short8*>(cbuf + 16384 + co);
                short8 b_l = *reinterpret_cast<const short8*>(cbuf + 24576 + co);
#pragma unroll
                for (int fm = 0; fm < 4; ++fm) {
                    acc[fm][fn] = __builtin_amdgcn_mfma_f32_16x16x32_bf16(a_h[fm], b_h, acc[fm][fn], 0, 0, 0);
                    acc[fm][fn] = __builtin_amdgcn_mfma_f32_16x16x32_bf16(a_h[fm], b_l, acc[fm][fn], 0, 0, 0);
                    acc[fm][fn] = __builtin_amdgcn_mfma_f32_16x16x32_bf16(a_l[fm], b_h, acc[fm][fn], 0, 0, 0);
                }
            }
        }
        // end of codebook tile: fold norms, per-lane pre-min over 4 cols, top2 update
        if (dc == 7) {
            const int cbase = ks * KC + ct * 128 + wc * 64 + l15;
            float nn0 = norms[cbase], nn1 = norms[cbase + 16];
            float nn2 = norms[cbase + 32], nn3 = norms[cbase + 48];
#pragma unroll
            for (int fm = 0; fm < 4; ++fm)
#pragma unroll
                for (int r = 0; r < 4; ++r) {
                    float s0 = fmaf(-2.f, acc[fm][0][r], nn0);
                    float s1 = fmaf(-2.f, acc[fm][1][r], nn1);
                    float s2 = fmaf(-2.f, acc[fm][2][r], nn2);
                    float s3 = fmaf(-2.f, acc[fm][3][r], nn3);
                    float sm = s0; int sj = cbase;
                    if (s1 < sm) { sm = s1; sj = cbase + 16; }
                    if (s2 < sm) { sm = s2; sj = cbase + 32; }
                    if (s3 < sm) { sm = s3; sj = cbase + 48; }
                    const int q = fm * 4 + r;
                    if (sm < v1[q]) { v2[q] = v1[q]; i2[q] = i1[q]; v1[q] = sm; i1[q] = sj; }
                    else if (sm < v2[q]) { v2[q] = sm; i2[q] = sj; }
                }
        }
        __syncthreads();  // drains vmcnt(0): next buffer staged; also protects buffer reuse
    }

    // ---- butterfly top2 merge across the 16 column-lanes ----
#pragma unroll
    for (int m = 1; m < 16; m <<= 1) {
#pragma unroll
        for (int q = 0; q < 16; ++q) {
            float ov1 = __shfl_xor(v1[q], m, 64); int oi1 = __shfl_xor(i1[q], m, 64);
            float ov2 = __shfl_xor(v2[q], m, 64); int oi2 = __shfl_xor(i2[q], m, 64);
            bool bl = (ov1 < v1[q]) || (ov1 == v1[q] && oi1 < i1[q]);
            float fv = bl ? ov1 : v1[q]; int fi = bl ? oi1 : i1[q];
            float rv = bl ? v1[q] : ov1; int ri = bl ? i1[q] : oi1;
            float sv = bl ? ov2 : v2[q]; int si = bl ? oi2 : i2[q];
            bool b2 = (sv < rv) || (sv == rv && si < ri);
            v1[q] = fv; i1[q] = fi;
            v2[q] = b2 ? sv : rv; i2[q] = b2 ? si : ri;
        }
    }
    // write per-(row, colwave) merged top2 to LDS  (tiles are dead: all waves past final barrier)
    if (l15 == 0) {
#pragma unroll
        for (int q = 0; q < 16; ++q) {
            const int fm = q >> 2, r = q & 3;
            const int row128 = wr * 64 + fm * 16 + l4 * 4 + r;
            reinterpret_cast<int4*>(smem)[row128 * 2 + wc] =
                make_int4(__float_as_int(v1[q]), i1[q], __float_as_int(v2[q]), i2[q]);
        }
    }
    __syncthreads();
    if (t < 128) {
        int4 A = reinterpret_cast<int4*>(smem)[t * 2 + 0];
        int4 B = reinterpret_cast<int4*>(smem)[t * 2 + 1];
        float a1 = __int_as_float(A.x), a2 = __int_as_float(A.z);
        int aj1 = A.y, aj2 = A.w;
        float b1 = __int_as_float(B.x), b2v = __int_as_float(B.z);
        int bj1 = B.y, bj2 = B.w;
        bool bl = (b1 < a1) || (b1 == a1 && bj1 < aj1);
        float f1 = bl ? b1 : a1; int fj1 = bl ? bj1 : aj1;
        float rv = bl ? a1 : b1; int rj = bl ? aj1 : bj1;
        float sv = bl ? b2v : a2; int sj = bl ? bj2 : aj2;
        bool c2 = (sv < rv) || (sv == rv && sj < rj);
        float f2 = c2 ? sv : rv; int fj2 = c2 ? sj : rj;
        const int n = rb * 128 + t;
        cand_val[n * 8 + ks * 2 + 0] = f1; cand_idx[n * 8 + ks * 2 + 0] = fj1;
        cand_val[n * 8 + ks * 2 + 1] = f2; cand_idx[n * 8 + ks * 2 + 1] = fj2;
    }
}

// ---------------- merge splits + exact fp32 rescore of top-2 ----------------
// one wave per row; grid must cover NROWS*64 threads = 4096 blocks of 256
__global__ void k_merge(const float* __restrict__ z, const float* __restrict__ cb,
                        const float* __restrict__ norms,
                        const float* __restrict__ cand_val, const int* __restrict__ cand_idx,
                        int* __restrict__ fidx) {
    const int gid = blockIdx.x * blockDim.x + threadIdx.x;
    const int wid = gid >> 6;          // row id 0..16383
    const int lane = threadIdx.x & 63;
    float v1 = 3.4e38f, v2 = 3.4e38f; int i1 = 0, i2 = 0;
#pragma unroll
    for (int c = 0; c < 8; ++c) {
        float v = cand_val[wid * 8 + c]; int i = cand_idx[wid * 8 + c];
        bool lt1 = (v < v1) || (v == v1 && i < i1);
        bool lt2 = (v < v2) || (v == v2 && i < i2);
        if (lt1) { v2 = v1; i2 = i1; v1 = v; i1 = i; }
        else if (lt2) { v2 = v; i2 = i; }
    }
    const float4 zq = *reinterpret_cast<const float4*>(z + (size_t)wid * DDIM + lane * 4);
    float d[2]; int ii[2] = { i1, i2 };
#pragma unroll
    for (int c = 0; c < 2; ++c) {
        const float4 e4 = *reinterpret_cast<const float4*>(cb + (size_t)ii[c] * DDIM + lane * 4);
        float s = zq.x * e4.x + zq.y * e4.y + zq.z * e4.z + zq.w * e4.w;
#pragma unroll
        for (int m = 32; m > 0; m >>= 1) s += __shfl_xor(s, m, 64);
        d[c] = norms[ii[c]] - 2.f * s;
    }
    const int best = (d[1] < d[0] || (d[1] == d[0] && ii[1] < ii[0])) ? ii[1] : ii[0];
    if (lane == 0) fidx[wid] = best;
}

// ---------------- copy z_e, gather z_q, loss partials ----------------
__global__ void k_finalize(const float* __restrict__ z, const float* __restrict__ cb,
                           const int* __restrict__ fidx, float* __restrict__ out,
                           float* __restrict__ partials) {
    const int i4 = blockIdx.x * blockDim.x + threadIdx.x;
    float4 zv = *reinterpret_cast<const float4*>(z + (size_t)i4 * 4);
    *reinterpret_cast<float4*>(out + (size_t)i4 * 4) = zv;
    const int n = i4 >> 6;
    const int d0 = (i4 & 63) << 2;
    const int idx = fidx[n];
    float4 q = *reinterpret_cast<const float4*>(cb + (size_t)idx * DDIM + d0);
    float* oq = out + (size_t)ND + 1 + (size_t)i4 * 4;
    oq[0] = q.x; oq[1] = q.y; oq[2] = q.z; oq[3] = q.w;
    const float dx = q.x - zv.x, dy = q.y - zv.y, dz = q.z - zv.z, dw = q.w - zv.w;
    float s = dx * dx + dy * dy + dz * dz + dw * dw;
#pragma unroll
    for (int off = 32; off > 0; off >>= 1) s += __shfl_xor(s, off, 64);
    __shared__ float sm[4];
    const int wv = threadIdx.x >> 6, ln = threadIdx.x & 63;
    if (ln == 0) sm[wv] = s;
    __syncthreads();
    if (threadIdx.x == 0) partials[blockIdx.x] = sm[0] + sm[1] + sm[2] + sm[3];
}

__global__ void k_loss(const float* __restrict__ partials, float* __restrict__ out) {
    float s = 0.f;
    for (int i = threadIdx.x; i < 4096; i += 256) s += partials[i];
#pragma unroll
    for (int off = 32; off > 0; off >>= 1) s += __shfl_xor(s, off, 64);
    __shared__ float sm[4];
    const int wv = threadIdx.x >> 6, ln = threadIdx.x & 63;
    if (ln == 0) sm[wv] = s;
    __syncthreads();
    if (threadIdx.x == 0) out[ND] = 2.0f * (sm[0] + sm[1] + sm[2] + sm[3]) / (float)ND;
}

extern "C" void kernel_launch(void* const* d_in, const int* in_sizes, int n_in,
                              void* d_out, int out_size, void* d_ws, size_t ws_size,
                              hipStream_t stream) {
    const float* z = (const float*)d_in[0];   // [16384, 256]
    const float* cb = (const float*)d_in[1];  // [8192, 256]
    float* out = (float*)d_out;               // z_e[ND], loss[1], z_q[ND]
    float* ws = (float*)d_ws;

    // small scratch in ws (~120 KB)
    float* norms = ws;                        // 8192
    int* fidx = (int*)(ws + 8192);            // 16384
    float* partials = ws + 8192 + 16384;      // 4096

    // big scratch carved from d_out (33.55 MB total; fully overwritten by k_finalize+k_loss)
    char* ob = (char*)d_out;
    unsigned short* zh = (unsigned short*)(ob);                     // 8.39 MB
    unsigned short* zl = (unsigned short*)(ob + 8388608);           // 8.39 MB
    unsigned short* eh = (unsigned short*)(ob + 16777216);          // 4.19 MB
    unsigned short* el = (unsigned short*)(ob + 20971520);          // 4.19 MB
    float* cand_val = (float*)(ob + 25165824);                      // 0.52 MB
    int* cand_idx = (int*)(ob + 25690112);                          // 0.52 MB (ends 26.2 MB < 33.5 MB)

    k_split<<<dim3(4096), dim3(256), 0, stream>>>(z, zh, zl);
    k_split<<<dim3(2048), dim3(256), 0, stream>>>(cb, eh, el);
    k_norms<<<dim3(2048), dim3(256), 0, stream>>>(cb, norms);
    k_score<<<dim3(128, 4), dim3(256), 0, stream>>>(zh, zl, eh, el, norms, cand_val, cand_idx);
    k_merge<<<dim3(4096), dim3(256), 0, stream>>>(z, cb, norms, cand_val, cand_idx, fidx);
    k_finalize<<<dim3(4096), dim3(256), 0, stream>>>(z, cb, fidx, out, partials);
    k_loss<<<dim3(1), dim3(256), 0, stream>>>(partials, out);
}

// Round 5
// 272.081 us; speedup vs baseline: 1.2847x; 1.2847x over previous
//
#include <hip/hip_runtime.h>
#include <stdint.h>

typedef short short8 __attribute__((ext_vector_type(8)));
typedef float f32x4 __attribute__((ext_vector_type(4)));

#define DDIM 256
#define NROWS 16384
#define KCB 8192
#define KSPLIT 4
#define KC 2048
#define ND 4194304

// async global -> LDS, 16 bytes per lane (dest = wave-uniform base + lane*16)
__device__ __forceinline__ void gll16(const void* g, void* l) {
    __builtin_amdgcn_global_load_lds(
        (const __attribute__((address_space(1))) unsigned int*)g,
        (__attribute__((address_space(3))) unsigned int*)l, 16, 0, 0);
}

__device__ __forceinline__ unsigned short bf16_rne(float x) {
    unsigned u = __float_as_uint(x);
    unsigned r = (u + 0x7FFFu + ((u >> 16) & 1u)) >> 16;
    return (unsigned short)r;
}

// ---------------- fused: split z, split cb + codebook norms ----------------
__global__ void k_prep(const float* __restrict__ z, const float* __restrict__ cb,
                       unsigned short* __restrict__ zh, unsigned short* __restrict__ zl,
                       unsigned short* __restrict__ eh, unsigned short* __restrict__ el,
                       float* __restrict__ norms) {
    const int b = blockIdx.x, t = threadIdx.x;
    const bool isz = (b < 4096);
    const float* src = isz ? z : cb;
    unsigned short* hi = isz ? zh : eh;
    unsigned short* lo = isz ? zl : el;
    const int i = (isz ? b : (b - 4096)) * 256 + t;
    float4 v = reinterpret_cast<const float4*>(src)[i];
    ushort4 h, l;
    h.x = bf16_rne(v.x); l.x = bf16_rne(v.x - __uint_as_float((unsigned)h.x << 16));
    h.y = bf16_rne(v.y); l.y = bf16_rne(v.y - __uint_as_float((unsigned)h.y << 16));
    h.z = bf16_rne(v.z); l.z = bf16_rne(v.z - __uint_as_float((unsigned)h.z << 16));
    h.w = bf16_rne(v.w); l.w = bf16_rne(v.w - __uint_as_float((unsigned)h.w << 16));
    reinterpret_cast<ushort4*>(hi)[i] = h;
    reinterpret_cast<ushort4*>(lo)[i] = l;
    if (!isz) {
        float s = v.x * v.x + v.y * v.y + v.z * v.z + v.w * v.w;
#pragma unroll
        for (int off = 32; off > 0; off >>= 1) s += __shfl_xor(s, off, 64);
        if ((t & 63) == 0) norms[i >> 6] = s;
    }
}

// stage one 64col x 64d B-chunk (eh+el) into LDS buffer, swizzled source / linear dest
__device__ __forceinline__ void stageB(char* sdst, const char* pe, const char* pl, int voff0) {
    gll16(pe + voff0,         sdst);            // eh cols 0-31
    gll16(pe + voff0 + 16384, sdst + 4096);     // eh cols 32-63
    gll16(pl + voff0,         sdst + 8192);     // el cols 0-31
    gll16(pl + voff0 + 16384, sdst + 12288);    // el cols 32-63
}

// ---------------- MFMA score + top-2 argmin (A-in-registers) ----------------
// approx score(n,k) = ||e_k||^2 - 2*(zh.eh + zh.el + zl.eh)
__launch_bounds__(256, 2)
__global__ void k_score(const unsigned short* __restrict__ zh, const unsigned short* __restrict__ zl,
                        const unsigned short* __restrict__ eh, const unsigned short* __restrict__ el,
                        const float* __restrict__ norms,
                        float* __restrict__ cand_val, int* __restrict__ cand_idx) {
    __shared__ char smem[32768];   // [p][eh|el][64 cols][128 B], XOR-swizzled 16B slots

    const int rb = blockIdx.x;     // row block 0..127
    const int ks = blockIdx.y;     // codebook split 0..3
    const int t = threadIdx.x, w = t >> 6, lane = t & 63;
    const int l15 = lane & 15, l4 = lane >> 4;

    // staging: thread t -> col colq (and colq+32), slot c = t&7; source chunk g = c ^ (col&7)
    const int colq = t >> 3;
    const int voff0 = colq * 512 + (((t & 7) ^ (colq & 7)) * 16);

    // B-fragment LDS read offsets (col = l15, 16B slot X = kc*4+l4, swizzle ^ (col&7))
    int voffB[2];
#pragma unroll
    for (int kc = 0; kc < 2; ++kc)
        voffB[kc] = l15 * 128 + ((((kc * 4) + l4) ^ (lane & 7)) * 16);

    // A in registers: wave owns rows rb*128 + w*32 .. +32 (2 rfrags of 16)
    short8 Ah[2][8], Al[2][8];
    {
        const size_t base0 = ((size_t)(rb * 128 + w * 32 + l15)) * DDIM + l4 * 8;
#pragma unroll
        for (int r = 0; r < 2; ++r)
#pragma unroll
            for (int kk = 0; kk < 8; ++kk) {
                Ah[r][kk] = *reinterpret_cast<const short8*>(zh + base0 + r * 16 * DDIM + kk * 32);
                Al[r][kk] = *reinterpret_cast<const short8*>(zl + base0 + r * 16 * DDIM + kk * 32);
            }
    }

    // per-lane top2 over 8 (row-slot) cells; idx packed: lo16 = i1, hi16 = i2 (local col 0..2047)
    float v1[8], v2[8]; unsigned pk[8];
#pragma unroll
    for (int s = 0; s < 8; ++s) { v1[s] = 3.4e38f; v2[s] = 3.4e38f; pk[s] = 0; }

    size_t ub = (size_t)(ks * KC) * 512;   // byte base of current 64-col ct tile
    stageB(smem + t * 16, (const char*)eh + ub, (const char*)el + ub, voff0);
    __syncthreads();

    for (int ct = 0; ct < 32; ++ct) {
        f32x4 acc[2][4];
#pragma unroll
        for (int r = 0; r < 2; ++r)
#pragma unroll
            for (int cf = 0; cf < 4; ++cf) acc[r][cf] = (f32x4){0.f, 0.f, 0.f, 0.f};

#pragma unroll
        for (int dc = 0; dc < 4; ++dc) {
            const int p = dc & 1;
            if (dc < 3) {
                stageB(smem + (p ^ 1) * 16384 + t * 16,
                       (const char*)eh + ub + (dc + 1) * 128,
                       (const char*)el + ub + (dc + 1) * 128, voff0);
            } else if (ct < 31) {
                stageB(smem + (p ^ 1) * 16384 + t * 16,
                       (const char*)eh + ub + 32768,
                       (const char*)el + ub + 32768, voff0);
            }
            const char* cb0 = smem + p * 16384;
#pragma unroll
            for (int cf = 0; cf < 4; ++cf) {
#pragma unroll
                for (int kc = 0; kc < 2; ++kc) {
                    short8 bh = *reinterpret_cast<const short8*>(cb0 + cf * 2048 + voffB[kc]);
                    short8 bl = *reinterpret_cast<const short8*>(cb0 + 8192 + cf * 2048 + voffB[kc]);
                    const int kk = dc * 2 + kc;
#pragma unroll
                    for (int r = 0; r < 2; ++r) {
                        acc[r][cf] = __builtin_amdgcn_mfma_f32_16x16x32_bf16(Ah[r][kk], bh, acc[r][cf], 0, 0, 0);
                        acc[r][cf] = __builtin_amdgcn_mfma_f32_16x16x32_bf16(Ah[r][kk], bl, acc[r][cf], 0, 0, 0);
                        acc[r][cf] = __builtin_amdgcn_mfma_f32_16x16x32_bf16(Al[r][kk], bh, acc[r][cf], 0, 0, 0);
                    }
                }
            }
            __syncthreads();
        }

        // fold norms, min over 4 col-frags, running top2 (registers only)
        {
            const int nb = ks * KC + ct * 64 + l15;
            const float nn0 = norms[nb], nn1 = norms[nb + 16];
            const float nn2 = norms[nb + 32], nn3 = norms[nb + 48];
            const int cl0 = ct * 64 + l15;
#pragma unroll
            for (int r = 0; r < 2; ++r)
#pragma unroll
                for (int reg = 0; reg < 4; ++reg) {
                    float s0 = fmaf(-2.f, acc[r][0][reg], nn0);
                    float s1 = fmaf(-2.f, acc[r][1][reg], nn1);
                    float s2 = fmaf(-2.f, acc[r][2][reg], nn2);
                    float s3 = fmaf(-2.f, acc[r][3][reg], nn3);
                    float sm = s0; int sj = cl0;
                    if (s1 < sm) { sm = s1; sj = cl0 + 16; }
                    if (s2 < sm) { sm = s2; sj = cl0 + 32; }
                    if (s3 < sm) { sm = s3; sj = cl0 + 48; }
                    const int s = r * 4 + reg;
                    if (sm < v1[s]) { v2[s] = v1[s]; pk[s] = (pk[s] << 16) | (unsigned)sj; v1[s] = sm; }
                    else if (sm < v2[s]) { v2[s] = sm; pk[s] = (pk[s] & 0xFFFFu) | ((unsigned)sj << 16); }
                }
        }
        ub += 32768;
    }

    // butterfly top2 merge across the 16 column-lanes (l15); l4 preserved
#pragma unroll
    for (int m = 1; m < 16; m <<= 1) {
#pragma unroll
        for (int s = 0; s < 8; ++s) {
            float ov1 = __shfl_xor(v1[s], m, 64);
            float ov2 = __shfl_xor(v2[s], m, 64);
            unsigned opk = (unsigned)__shfl_xor((int)pk[s], m, 64);
            const int ia = (int)(pk[s] & 0xFFFFu), ib = (int)(opk & 0xFFFFu);
            bool bl = (ov1 < v1[s]) || (ov1 == v1[s] && ib < ia);
            float f1 = bl ? ov1 : v1[s]; int fi = bl ? ib : ia;
            float rv = bl ? v1[s] : ov1; int ri = bl ? ia : ib;
            float sv = bl ? ov2 : v2[s]; int si = bl ? (int)(opk >> 16) : (int)(pk[s] >> 16);
            bool b2 = (sv < rv) || (sv == rv && si < ri);
            v1[s] = f1; v2[s] = b2 ? sv : rv;
            pk[s] = (unsigned)fi | ((unsigned)(b2 ? si : ri) << 16);
        }
    }
    if (l15 == 0) {
#pragma unroll
        for (int s = 0; s < 8; ++s) {
            const int row = (s >> 2) * 16 + l4 * 4 + (s & 3);
            const int n = rb * 128 + w * 32 + row;
            cand_val[n * 8 + ks * 2 + 0] = v1[s];
            cand_val[n * 8 + ks * 2 + 1] = v2[s];
            cand_idx[n * 8 + ks * 2 + 0] = ks * KC + (int)(pk[s] & 0xFFFFu);
            cand_idx[n * 8 + ks * 2 + 1] = ks * KC + (int)(pk[s] >> 16);
        }
    }
}

// ---------------- merge splits + exact fp32 rescore of top-2 ----------------
// one wave per row; grid = 4096 blocks of 256
__global__ void k_merge(const float* __restrict__ z, const float* __restrict__ cb,
                        const float* __restrict__ norms,
                        const float* __restrict__ cand_val, const int* __restrict__ cand_idx,
                        int* __restrict__ fidx) {
    const int gid = blockIdx.x * blockDim.x + threadIdx.x;
    const int wid = gid >> 6;          // row id 0..16383
    const int lane = threadIdx.x & 63;
    float v1 = 3.4e38f, v2 = 3.4e38f; int i1 = 0, i2 = 0;
#pragma unroll
    for (int c = 0; c < 8; ++c) {
        float v = cand_val[wid * 8 + c]; int i = cand_idx[wid * 8 + c];
        bool lt1 = (v < v1) || (v == v1 && i < i1);
        bool lt2 = (v < v2) || (v == v2 && i < i2);
        if (lt1) { v2 = v1; i2 = i1; v1 = v; i1 = i; }
        else if (lt2) { v2 = v; i2 = i; }
    }
    const float4 zq = *reinterpret_cast<const float4*>(z + (size_t)wid * DDIM + lane * 4);
    float d[2]; int ii[2] = { i1, i2 };
#pragma unroll
    for (int c = 0; c < 2; ++c) {
        const float4 e4 = *reinterpret_cast<const float4*>(cb + (size_t)ii[c] * DDIM + lane * 4);
        float s = zq.x * e4.x + zq.y * e4.y + zq.z * e4.z + zq.w * e4.w;
#pragma unroll
        for (int m = 32; m > 0; m >>= 1) s += __shfl_xor(s, m, 64);
        d[c] = norms[ii[c]] - 2.f * s;
    }
    const int best = (d[1] < d[0] || (d[1] == d[0] && ii[1] < ii[0])) ? ii[1] : ii[0];
    if (lane == 0) fidx[wid] = best;
}

// ---------------- copy z_e, gather z_q, loss partials ----------------
__global__ void k_finalize(const float* __restrict__ z, const float* __restrict__ cb,
                           const int* __restrict__ fidx, float* __restrict__ out,
                           float* __restrict__ partials) {
    const int i4 = blockIdx.x * blockDim.x + threadIdx.x;
    float4 zv = *reinterpret_cast<const float4*>(z + (size_t)i4 * 4);
    *reinterpret_cast<float4*>(out + (size_t)i4 * 4) = zv;
    const int n = i4 >> 6;
    const int d0 = (i4 & 63) << 2;
    const int idx = fidx[n];
    float4 q = *reinterpret_cast<const float4*>(cb + (size_t)idx * DDIM + d0);
    float* oq = out + (size_t)ND + 1 + (size_t)i4 * 4;
    oq[0] = q.x; oq[1] = q.y; oq[2] = q.z; oq[3] = q.w;
    const float dx = q.x - zv.x, dy = q.y - zv.y, dz = q.z - zv.z, dw = q.w - zv.w;
    float s = dx * dx + dy * dy + dz * dz + dw * dw;
#pragma unroll
    for (int off = 32; off > 0; off >>= 1) s += __shfl_xor(s, off, 64);
    __shared__ float sm[4];
    const int wv = threadIdx.x >> 6, ln = threadIdx.x & 63;
    if (ln == 0) sm[wv] = s;
    __syncthreads();
    if (threadIdx.x == 0) partials[blockIdx.x] = sm[0] + sm[1] + sm[2] + sm[3];
}

__global__ void k_loss(const float* __restrict__ partials, float* __restrict__ out) {
    float s = 0.f;
    for (int i = threadIdx.x; i < 4096; i += 256) s += partials[i];
#pragma unroll
    for (int off = 32; off > 0; off >>= 1) s += __shfl_xor(s, off, 64);
    __shared__ float sm[4];
    const int wv = threadIdx.x >> 6, ln = threadIdx.x & 63;
    if (ln == 0) sm[wv] = s;
    __syncthreads();
    if (threadIdx.x == 0) out[ND] = 2.0f * (sm[0] + sm[1] + sm[2] + sm[3]) / (float)ND;
}

extern "C" void kernel_launch(void* const* d_in, const int* in_sizes, int n_in,
                              void* d_out, int out_size, void* d_ws, size_t ws_size,
                              hipStream_t stream) {
    const float* z = (const float*)d_in[0];   // [16384, 256]
    const float* cb = (const float*)d_in[1];  // [8192, 256]
    float* out = (float*)d_out;               // z_e[ND], loss[1], z_q[ND]
    float* ws = (float*)d_ws;

    // small scratch in ws (~115 KB)
    float* norms = ws;                        // 8192
    int* fidx = (int*)(ws + 8192);            // 16384
    float* partials = ws + 8192 + 16384;      // 4096

    // big scratch carved from d_out (33.55 MB total; fully overwritten by k_finalize+k_loss)
    char* ob = (char*)d_out;
    unsigned short* zh = (unsigned short*)(ob);                     // 8.39 MB
    unsigned short* zl = (unsigned short*)(ob + 8388608);           // 8.39 MB
    unsigned short* eh = (unsigned short*)(ob + 16777216);          // 4.19 MB
    unsigned short* el = (unsigned short*)(ob + 20971520);          // 4.19 MB
    float* cand_val = (float*)(ob + 25165824);                      // 0.52 MB
    int* cand_idx = (int*)(ob + 25690112);                          // 0.52 MB (ends 26.2 MB < 33.5 MB)

    k_prep<<<dim3(6144), dim3(256), 0, stream>>>(z, cb, zh, zl, eh, el, norms);
    k_score<<<dim3(128, 4), dim3(256), 0, stream>>>(zh, zl, eh, el, norms, cand_val, cand_idx);
    k_merge<<<dim3(4096), dim3(256), 0, stream>>>(z, cb, norms, cand_val, cand_idx, fidx);
    k_finalize<<<dim3(4096), dim3(256), 0, stream>>>(z, cb, fidx, out, partials);
    k_loss<<<dim3(1), dim3(256), 0, stream>>>(partials, out);
}

// Round 8
// 266.029 us; speedup vs baseline: 1.3139x; 1.0227x over previous
//
#include <hip/hip_runtime.h>
#include <stdint.h>

typedef short short8 __attribute__((ext_vector_type(8)));
typedef float f32x4 __attribute__((ext_vector_type(4)));

#define DDIM 256
#define NROWS 16384
#define KCB 8192
#define KSPLIT 4
#define KC 2048
#define ND 4194304

// async global -> LDS, 16 bytes per lane (dest = wave-uniform base + lane*16)
__device__ __forceinline__ void gll16(const void* g, void* l) {
    __builtin_amdgcn_global_load_lds(
        (const __attribute__((address_space(1))) unsigned int*)g,
        (__attribute__((address_space(3))) unsigned int*)l, 16, 0, 0);
}

__device__ __forceinline__ unsigned short bf16_rne(float x) {
    unsigned u = __float_as_uint(x);
    unsigned r = (u + 0x7FFFu + ((u >> 16) & 1u)) >> 16;
    return (unsigned short)r;
}

// ---------------- fused: split z, split cb + codebook norms ----------------
__global__ void k_prep(const float* __restrict__ z, const float* __restrict__ cb,
                       unsigned short* __restrict__ zh, unsigned short* __restrict__ zl,
                       unsigned short* __restrict__ eh, unsigned short* __restrict__ el,
                       float* __restrict__ norms) {
    const int b = blockIdx.x, t = threadIdx.x;
    const bool isz = (b < 4096);
    const float* src = isz ? z : cb;
    unsigned short* hi = isz ? zh : eh;
    unsigned short* lo = isz ? zl : el;
    const int i = (isz ? b : (b - 4096)) * 256 + t;
    float4 v = reinterpret_cast<const float4*>(src)[i];
    ushort4 h, l;
    h.x = bf16_rne(v.x); l.x = bf16_rne(v.x - __uint_as_float((unsigned)h.x << 16));
    h.y = bf16_rne(v.y); l.y = bf16_rne(v.y - __uint_as_float((unsigned)h.y << 16));
    h.z = bf16_rne(v.z); l.z = bf16_rne(v.z - __uint_as_float((unsigned)h.z << 16));
    h.w = bf16_rne(v.w); l.w = bf16_rne(v.w - __uint_as_float((unsigned)h.w << 16));
    reinterpret_cast<ushort4*>(hi)[i] = h;
    reinterpret_cast<ushort4*>(lo)[i] = l;
    if (!isz) {
        float s = v.x * v.x + v.y * v.y + v.z * v.z + v.w * v.w;
#pragma unroll
        for (int off = 32; off > 0; off >>= 1) s += __shfl_xor(s, off, 64);
        if ((t & 63) == 0) norms[i >> 6] = s;
    }
}

// ---------------- MFMA score + top-2 argmin (A-in-registers, 4-deep async pipe) ----------------
// approx score(n,k) = ||e_k||^2 - 2*(zh.eh + zh.el + zl.eh)
__launch_bounds__(256, 2)
__global__ void k_score(const unsigned short* __restrict__ zh, const unsigned short* __restrict__ zl,
                        const unsigned short* __restrict__ eh, const unsigned short* __restrict__ el,
                        const float* __restrict__ norms,
                        float* __restrict__ cand_val, int* __restrict__ cand_idx) {
    __shared__ char smem[65536];   // 4 buffers x [eh|el][64 cols][64 d], XOR-swizzled 16B slots

    const int rb = blockIdx.x;     // row block 0..127
    const int ks = blockIdx.y;     // codebook split 0..3
    const int t = threadIdx.x, w = t >> 6, lane = t & 63;
    const int l15 = lane & 15, l4 = lane >> 4;

    // staging: thread t -> col colq (and colq+32), slot c = t&7; source chunk g = c ^ (col&7)
    const int colq = t >> 3;
    const int voff0 = colq * 512 + (((t & 7) ^ (colq & 7)) * 16);

    // B-fragment LDS read offsets (col = l15, 16B slot X = kc*4+l4, swizzle ^ (col&7))
    int voffB[2];
#pragma unroll
    for (int kc = 0; kc < 2; ++kc)
        voffB[kc] = l15 * 128 + ((((kc * 4) + l4) ^ (lane & 7)) * 16);

    // A in registers: wave owns rows rb*128 + w*32 .. +32 (2 rfrags of 16)
    short8 Ah[2][8], Al[2][8];
    {
        const size_t base0 = ((size_t)(rb * 128 + w * 32 + l15)) * DDIM + l4 * 8;
#pragma unroll
        for (int r = 0; r < 2; ++r)
#pragma unroll
            for (int kk = 0; kk < 8; ++kk) {
                Ah[r][kk] = *reinterpret_cast<const short8*>(zh + base0 + r * 16 * DDIM + kk * 32);
                Al[r][kk] = *reinterpret_cast<const short8*>(zl + base0 + r * 16 * DDIM + kk * 32);
            }
    }

    const char* pe = (const char*)eh + (size_t)(ks * KC) * 512;
    const char* pl = (const char*)el + (size_t)(ks * KC) * 512;

    // stage global step s (64 cols x 64 d of eh+el) into buffer s&3
    auto stage = [&](int s) {
        const int off = (s >> 2) * 32768 + (s & 3) * 128;
        char* sdst = smem + (s & 3) * 16384 + t * 16;
        gll16(pe + off + voff0,         sdst);
        gll16(pe + off + voff0 + 16384, sdst + 4096);
        gll16(pl + off + voff0,         sdst + 8192);
        gll16(pl + off + voff0 + 16384, sdst + 12288);
    };

    // per-lane top2 over 8 (row-slot) cells; idx packed: lo16 = i1, hi16 = i2 (local col 0..2047)
    float v1[8], v2[8]; unsigned pk[8];
#pragma unroll
    for (int s = 0; s < 8; ++s) { v1[s] = 3.4e38f; v2[s] = 3.4e38f; pk[s] = 0; }

    f32x4 acc[2][4];

    auto compute = [&](int dc) {   // dc = buffer index = step&3 (compile-time at call sites)
        const char* cb0 = smem + dc * 16384;
        __builtin_amdgcn_s_setprio(1);
#pragma unroll
        for (int cf = 0; cf < 4; ++cf) {
#pragma unroll
            for (int kc = 0; kc < 2; ++kc) {
                short8 bh = *reinterpret_cast<const short8*>(cb0 + cf * 2048 + voffB[kc]);
                short8 bl = *reinterpret_cast<const short8*>(cb0 + 8192 + cf * 2048 + voffB[kc]);
                const int kk = dc * 2 + kc;
#pragma unroll
                for (int r = 0; r < 2; ++r) {
                    acc[r][cf] = __builtin_amdgcn_mfma_f32_16x16x32_bf16(Ah[r][kk], bh, acc[r][cf], 0, 0, 0);
                    acc[r][cf] = __builtin_amdgcn_mfma_f32_16x16x32_bf16(Ah[r][kk], bl, acc[r][cf], 0, 0, 0);
                    acc[r][cf] = __builtin_amdgcn_mfma_f32_16x16x32_bf16(Al[r][kk], bh, acc[r][cf], 0, 0, 0);
                }
            }
        }
        __builtin_amdgcn_s_setprio(0);
    };

    auto fold = [&](int ct) {      // fold norms, min over 4 col-frags, running top2
        const int nb = ks * KC + ct * 64 + l15;
        const float nn0 = norms[nb], nn1 = norms[nb + 16];
        const float nn2 = norms[nb + 32], nn3 = norms[nb + 48];
        const int cl0 = ct * 64 + l15;
#pragma unroll
        for (int r = 0; r < 2; ++r)
#pragma unroll
            for (int reg = 0; reg < 4; ++reg) {
                float s0 = fmaf(-2.f, acc[r][0][reg], nn0);
                float s1 = fmaf(-2.f, acc[r][1][reg], nn1);
                float s2 = fmaf(-2.f, acc[r][2][reg], nn2);
                float s3 = fmaf(-2.f, acc[r][3][reg], nn3);
                float sm = s0; int sj = cl0;
                if (s1 < sm) { sm = s1; sj = cl0 + 16; }
                if (s2 < sm) { sm = s2; sj = cl0 + 32; }
                if (s3 < sm) { sm = s3; sj = cl0 + 48; }
                const int s = r * 4 + reg;
                if (sm < v1[s]) { v2[s] = v1[s]; pk[s] = (pk[s] << 16) | (unsigned)sj; v1[s] = sm; }
                else if (sm < v2[s]) { v2[s] = sm; pk[s] = (pk[s] & 0xFFFFu) | ((unsigned)sj << 16); }
            }
    };

#define ACC_ZERO() do { \
    _Pragma("unroll") for (int r = 0; r < 2; ++r) \
    _Pragma("unroll") for (int cf = 0; cf < 4; ++cf) acc[r][cf] = (f32x4){0.f,0.f,0.f,0.f}; } while (0)

#define SYNC_V8()  do { asm volatile("s_waitcnt vmcnt(8) lgkmcnt(0)" ::: "memory"); \
    __builtin_amdgcn_sched_barrier(0); __builtin_amdgcn_s_barrier(); } while (0)
#define SYNC_V4()  do { asm volatile("s_waitcnt vmcnt(4) lgkmcnt(0)" ::: "memory"); \
    __builtin_amdgcn_sched_barrier(0); __builtin_amdgcn_s_barrier(); } while (0)
#define SYNC_V0()  do { asm volatile("s_waitcnt vmcnt(0) lgkmcnt(0)" ::: "memory"); \
    __builtin_amdgcn_sched_barrier(0); __builtin_amdgcn_s_barrier(); } while (0)

    // prologue: batches 0,1,2 in flight; wait batch 0 (vmcnt also drains the A-loads above)
    stage(0); stage(1); stage(2);
    asm volatile("s_waitcnt vmcnt(8)" ::: "memory");
    __builtin_amdgcn_sched_barrier(0);
    __builtin_amdgcn_s_barrier();

#pragma unroll 1
    for (int ct = 0; ct < 31; ++ct) {
        ACC_ZERO();
        const int s0 = ct * 4;
#pragma unroll
        for (int dc = 0; dc < 4; ++dc) {
            stage(s0 + dc + 3);
            compute(dc);
            SYNC_V8();
        }
        fold(ct);
    }
    // ct = 31 tail: steps 124..127
    ACC_ZERO();
    stage(127); compute(0); SYNC_V8();
    compute(1);             SYNC_V4();
    compute(2);             SYNC_V0();
    compute(3);
    fold(31);

    // ---- butterfly top2 merge across the 16 column-lanes (l15); l4 preserved ----
#pragma unroll
    for (int m = 1; m < 16; m <<= 1) {
#pragma unroll
        for (int s = 0; s < 8; ++s) {
            float ov1 = __shfl_xor(v1[s], m, 64);
            float ov2 = __shfl_xor(v2[s], m, 64);
            unsigned opk = (unsigned)__shfl_xor((int)pk[s], m, 64);
            const int ia = (int)(pk[s] & 0xFFFFu), ib = (int)(opk & 0xFFFFu);
            bool bl = (ov1 < v1[s]) || (ov1 == v1[s] && ib < ia);
            float f1 = bl ? ov1 : v1[s]; int fi = bl ? ib : ia;
            float rv = bl ? v1[s] : ov1; int ri = bl ? ia : ib;
            float sv = bl ? ov2 : v2[s]; int si = bl ? (int)(opk >> 16) : (int)(pk[s] >> 16);
            bool b2 = (sv < rv) || (sv == rv && si < ri);
            v1[s] = f1; v2[s] = b2 ? sv : rv;
            pk[s] = (unsigned)fi | ((unsigned)(b2 ? si : ri) << 16);
        }
    }
    __syncthreads();   // all compute done; smem safe to reuse
    if (l15 == 0) {
#pragma unroll
        for (int s = 0; s < 8; ++s) {
            const int row = (s >> 2) * 16 + l4 * 4 + (s & 3);
            const int n = w * 32 + row;
            reinterpret_cast<int4*>(smem)[n] =
                make_int4(__float_as_int(v1[s]), (int)(pk[s] & 0xFFFFu),
                          __float_as_int(v2[s]), (int)(pk[s] >> 16));
        }
    }
    __syncthreads();
    if (t < 128) {
        int4 A = reinterpret_cast<int4*>(smem)[t];
        const int n = rb * 128 + t;
        cand_val[n * 8 + ks * 2 + 0] = __int_as_float(A.x);
        cand_val[n * 8 + ks * 2 + 1] = __int_as_float(A.z);
        cand_idx[n * 8 + ks * 2 + 0] = ks * KC + A.y;
        cand_idx[n * 8 + ks * 2 + 1] = ks * KC + A.w;
    }
}

// ---------------- merge splits + exact fp32 rescore of top-2 ----------------
// one wave per row; grid = 4096 blocks of 256. MUST complete before k_finalize
// (k_finalize's z_q writes overwrite the cand_* region carved from d_out).
__global__ void k_merge(const float* __restrict__ z, const float* __restrict__ cb,
                        const float* __restrict__ norms,
                        const float* __restrict__ cand_val, const int* __restrict__ cand_idx,
                        int* __restrict__ fidx) {
    const int gid = blockIdx.x * blockDim.x + threadIdx.x;
    const int wid = gid >> 6;          // row id 0..16383
    const int lane = threadIdx.x & 63;
    float v1 = 3.4e38f, v2 = 3.4e38f; int i1 = 0, i2 = 0;
#pragma unroll
    for (int c = 0; c < 8; ++c) {
        float v = cand_val[wid * 8 + c]; int i = cand_idx[wid * 8 + c] & (KCB - 1);
        bool lt1 = (v < v1) || (v == v1 && i < i1);
        bool lt2 = (v < v2) || (v == v2 && i < i2);
        if (lt1) { v2 = v1; i2 = i1; v1 = v; i1 = i; }
        else if (lt2) { v2 = v; i2 = i; }
    }
    const float4 zq = *reinterpret_cast<const float4*>(z + (size_t)wid * DDIM + lane * 4);
    float d[2]; int ii[2] = { i1, i2 };
#pragma unroll
    for (int c = 0; c < 2; ++c) {
        const float4 e4 = *reinterpret_cast<const float4*>(cb + (size_t)ii[c] * DDIM + lane * 4);
        float s = zq.x * e4.x + zq.y * e4.y + zq.z * e4.z + zq.w * e4.w;
#pragma unroll
        for (int m = 32; m > 0; m >>= 1) s += __shfl_xor(s, m, 64);
        d[c] = norms[ii[c]] - 2.f * s;
    }
    const int best = (d[1] < d[0] || (d[1] == d[0] && ii[1] < ii[0])) ? ii[1] : ii[0];
    if (lane == 0) fidx[wid] = best;
}

// ---------------- copy z_e, gather z_q, loss partials ----------------
__global__ void k_finalize(const float* __restrict__ z, const float* __restrict__ cb,
                           const int* __restrict__ fidx, float* __restrict__ out,
                           float* __restrict__ partials) {
    const int i4 = blockIdx.x * blockDim.x + threadIdx.x;
    float4 zv = *reinterpret_cast<const float4*>(z + (size_t)i4 * 4);
    *reinterpret_cast<float4*>(out + (size_t)i4 * 4) = zv;
    const int n = i4 >> 6;
    const int d0 = (i4 & 63) << 2;
    const int idx = fidx[n] & (KCB - 1);
    float4 q = *reinterpret_cast<const float4*>(cb + (size_t)idx * DDIM + d0);
    float* oq = out + (size_t)ND + 1 + (size_t)i4 * 4;
    oq[0] = q.x; oq[1] = q.y; oq[2] = q.z; oq[3] = q.w;
    const float dx = q.x - zv.x, dy = q.y - zv.y, dz = q.z - zv.z, dw = q.w - zv.w;
    float s = dx * dx + dy * dy + dz * dz + dw * dw;
#pragma unroll
    for (int off = 32; off > 0; off >>= 1) s += __shfl_xor(s, off, 64);
    __shared__ float sm[4];
    const int wv = threadIdx.x >> 6, ln = threadIdx.x & 63;
    if (ln == 0) sm[wv] = s;
    __syncthreads();
    if (threadIdx.x == 0) partials[blockIdx.x] = sm[0] + sm[1] + sm[2] + sm[3];
}

__global__ void k_loss(const float* __restrict__ partials, float* __restrict__ out) {
    float s = 0.f;
    for (int i = threadIdx.x; i < 4096; i += 256) s += partials[i];
#pragma unroll
    for (int off = 32; off > 0; off >>= 1) s += __shfl_xor(s, off, 64);
    __shared__ float sm[4];
    const int wv = threadIdx.x >> 6, ln = threadIdx.x & 63;
    if (ln == 0) sm[wv] = s;
    __syncthreads();
    if (threadIdx.x == 0) out[ND] = 2.0f * (sm[0] + sm[1] + sm[2] + sm[3]) / (float)ND;
}

extern "C" void kernel_launch(void* const* d_in, const int* in_sizes, int n_in,
                              void* d_out, int out_size, void* d_ws, size_t ws_size,
                              hipStream_t stream) {
    const float* z = (const float*)d_in[0];   // [16384, 256]
    const float* cb = (const float*)d_in[1];  // [8192, 256]
    float* out = (float*)d_out;               // z_e[ND], loss[1], z_q[ND]
    float* ws = (float*)d_ws;

    // small scratch in ws (~115 KB)
    float* norms = ws;                        // 8192
    int* fidx = (int*)(ws + 8192);            // 16384
    float* partials = ws + 8192 + 16384;      // 4096

    // big scratch carved from d_out (33.55 MB total; cand_* consumed by k_merge BEFORE
    // k_finalize overwrites d_out with the real outputs)
    char* ob = (char*)d_out;
    unsigned short* zh = (unsigned short*)(ob);                     // 8.39 MB
    unsigned short* zl = (unsigned short*)(ob + 8388608);           // 8.39 MB
    unsigned short* eh = (unsigned short*)(ob + 16777216);          // 4.19 MB
    unsigned short* el = (unsigned short*)(ob + 20971520);          // 4.19 MB
    float* cand_val = (float*)(ob + 25165824);                      // 0.52 MB
    int* cand_idx = (int*)(ob + 25690112);                          // 0.52 MB (ends 26.2 MB < 33.5 MB)

    k_prep<<<dim3(6144), dim3(256), 0, stream>>>(z, cb, zh, zl, eh, el, norms);
    k_score<<<dim3(128, 4), dim3(256), 0, stream>>>(zh, zl, eh, el, norms, cand_val, cand_idx);
    k_merge<<<dim3(4096), dim3(256), 0, stream>>>(z, cb, norms, cand_val, cand_idx, fidx);
    k_finalize<<<dim3(4096), dim3(256), 0, stream>>>(z, cb, fidx, out, partials);
    k_loss<<<dim3(1), dim3(256), 0, stream>>>(partials, out);
}

// Round 9
// 259.769 us; speedup vs baseline: 1.3456x; 1.0241x over previous
//
#include <hip/hip_runtime.h>
#include <stdint.h>

typedef short short8 __attribute__((ext_vector_type(8)));
typedef float f32x4 __attribute__((ext_vector_type(4)));

#define DDIM 256
#define NROWS 16384
#define KCB 8192
#define KSPLIT 4
#define KC 2048
#define ND 4194304

// async global -> LDS, 16 bytes per lane (dest = wave-uniform base + lane*16)
__device__ __forceinline__ void gll16(const void* g, void* l) {
    __builtin_amdgcn_global_load_lds(
        (const __attribute__((address_space(1))) unsigned int*)g,
        (__attribute__((address_space(3))) unsigned int*)l, 16, 0, 0);
}

__device__ __forceinline__ unsigned short bf16_rne(float x) {
    unsigned u = __float_as_uint(x);
    unsigned r = (u + 0x7FFFu + ((u >> 16) & 1u)) >> 16;
    return (unsigned short)r;
}

// ---------------- fused: split z, split cb + codebook norms ----------------
__global__ void k_prep(const float* __restrict__ z, const float* __restrict__ cb,
                       unsigned short* __restrict__ zh, unsigned short* __restrict__ zl,
                       unsigned short* __restrict__ eh, unsigned short* __restrict__ el,
                       float* __restrict__ norms) {
    const int b = blockIdx.x, t = threadIdx.x;
    const bool isz = (b < 4096);
    const float* src = isz ? z : cb;
    unsigned short* hi = isz ? zh : eh;
    unsigned short* lo = isz ? zl : el;
    const int i = (isz ? b : (b - 4096)) * 256 + t;
    float4 v = reinterpret_cast<const float4*>(src)[i];
    ushort4 h, l;
    h.x = bf16_rne(v.x); l.x = bf16_rne(v.x - __uint_as_float((unsigned)h.x << 16));
    h.y = bf16_rne(v.y); l.y = bf16_rne(v.y - __uint_as_float((unsigned)h.y << 16));
    h.z = bf16_rne(v.z); l.z = bf16_rne(v.z - __uint_as_float((unsigned)h.z << 16));
    h.w = bf16_rne(v.w); l.w = bf16_rne(v.w - __uint_as_float((unsigned)h.w << 16));
    reinterpret_cast<ushort4*>(hi)[i] = h;
    reinterpret_cast<ushort4*>(lo)[i] = l;
    if (!isz) {
        float s = v.x * v.x + v.y * v.y + v.z * v.z + v.w * v.w;
#pragma unroll
        for (int off = 32; off > 0; off >>= 1) s += __shfl_xor(s, off, 64);
        if ((t & 63) == 0) norms[i >> 6] = s;
    }
}

// ---------------- MFMA score + top-2 argmin (A-in-registers, 4-deep async pipe) ----------------
// approx score(n,k) = ||e_k||^2 - 2*(zh.eh + zh.el + zl.eh)
__launch_bounds__(256, 2)
__global__ void k_score(const unsigned short* __restrict__ zh, const unsigned short* __restrict__ zl,
                        const unsigned short* __restrict__ eh, const unsigned short* __restrict__ el,
                        const float* __restrict__ norms,
                        float* __restrict__ cand_val, int* __restrict__ cand_idx) {
    __shared__ char smem[65536];   // 4 buffers x [eh|el][64 cols][64 d], XOR-swizzled 16B slots

    const int rb = blockIdx.x;     // row block 0..127
    const int ks = blockIdx.y;     // codebook split 0..3
    const int t = threadIdx.x, w = t >> 6, lane = t & 63;
    const int l15 = lane & 15, l4 = lane >> 4;

    // staging: thread t -> col colq (and colq+32), slot c = t&7; source chunk g = c ^ (col&7)
    const int colq = t >> 3;
    const int voff0 = colq * 512 + (((t & 7) ^ (colq & 7)) * 16);

    // B-fragment LDS read offsets (col = l15, 16B slot X = kc*4+l4, swizzle ^ (col&7))
    int voffB[2];
#pragma unroll
    for (int kc = 0; kc < 2; ++kc)
        voffB[kc] = l15 * 128 + ((((kc * 4) + l4) ^ (lane & 7)) * 16);

    // A in registers: wave owns rows rb*128 + w*32 .. +32 (2 rfrags of 16)
    short8 Ah[2][8], Al[2][8];
    {
        const size_t base0 = ((size_t)(rb * 128 + w * 32 + l15)) * DDIM + l4 * 8;
#pragma unroll
        for (int r = 0; r < 2; ++r)
#pragma unroll
            for (int kk = 0; kk < 8; ++kk) {
                Ah[r][kk] = *reinterpret_cast<const short8*>(zh + base0 + r * 16 * DDIM + kk * 32);
                Al[r][kk] = *reinterpret_cast<const short8*>(zl + base0 + r * 16 * DDIM + kk * 32);
            }
    }
    // PIN the A fragments: forbid rematerialization / reloads inside the loop.
    // (Reloads would both add VMEM traffic and corrupt the counted-vmcnt pipeline.)
#pragma unroll
    for (int r = 0; r < 2; ++r)
#pragma unroll
        for (int kk = 0; kk < 8; ++kk) {
            asm volatile("" : "+v"(Ah[r][kk]));
            asm volatile("" : "+v"(Al[r][kk]));
        }

    const char* pe = (const char*)eh + (size_t)(ks * KC) * 512;
    const char* pl = (const char*)el + (size_t)(ks * KC) * 512;

    // stage global step s (64 cols x 64 d of eh+el) into buffer s&3
    auto stage = [&](int s) {
        const int off = (s >> 2) * 32768 + (s & 3) * 128;
        char* sdst = smem + (s & 3) * 16384 + t * 16;
        gll16(pe + off + voff0,         sdst);
        gll16(pe + off + voff0 + 16384, sdst + 4096);
        gll16(pl + off + voff0,         sdst + 8192);
        gll16(pl + off + voff0 + 16384, sdst + 12288);
    };

    // per-lane top2 over 8 (row-slot) cells; idx packed: lo16 = i1, hi16 = i2 (local col 0..2047)
    float v1[8], v2[8]; unsigned pk[8];
#pragma unroll
    for (int s = 0; s < 8; ++s) { v1[s] = 3.4e38f; v2[s] = 3.4e38f; pk[s] = 0; }

    f32x4 acc[2][4];

    auto compute = [&](int dc) {   // dc = buffer index = step&3 (compile-time at call sites)
        const char* cb0 = smem + dc * 16384;
        __builtin_amdgcn_s_setprio(1);
#pragma unroll
        for (int cf = 0; cf < 4; ++cf) {
#pragma unroll
            for (int kc = 0; kc < 2; ++kc) {
                short8 bh = *reinterpret_cast<const short8*>(cb0 + cf * 2048 + voffB[kc]);
                short8 bl = *reinterpret_cast<const short8*>(cb0 + 8192 + cf * 2048 + voffB[kc]);
                const int kk = dc * 2 + kc;
#pragma unroll
                for (int r = 0; r < 2; ++r) {
                    acc[r][cf] = __builtin_amdgcn_mfma_f32_16x16x32_bf16(Ah[r][kk], bh, acc[r][cf], 0, 0, 0);
                    acc[r][cf] = __builtin_amdgcn_mfma_f32_16x16x32_bf16(Ah[r][kk], bl, acc[r][cf], 0, 0, 0);
                    acc[r][cf] = __builtin_amdgcn_mfma_f32_16x16x32_bf16(Al[r][kk], bh, acc[r][cf], 0, 0, 0);
                }
            }
        }
        __builtin_amdgcn_s_setprio(0);
    };

    // fold norms, min over 4 col-frags, running top2 (norms preloaded per ct)
    auto fold = [&](int ct, float nn0, float nn1, float nn2, float nn3) {
        const int cl0 = ct * 64 + l15;
#pragma unroll
        for (int r = 0; r < 2; ++r)
#pragma unroll
            for (int reg = 0; reg < 4; ++reg) {
                float s0 = fmaf(-2.f, acc[r][0][reg], nn0);
                float s1 = fmaf(-2.f, acc[r][1][reg], nn1);
                float s2 = fmaf(-2.f, acc[r][2][reg], nn2);
                float s3 = fmaf(-2.f, acc[r][3][reg], nn3);
                float sm = s0; int sj = cl0;
                if (s1 < sm) { sm = s1; sj = cl0 + 16; }
                if (s2 < sm) { sm = s2; sj = cl0 + 32; }
                if (s3 < sm) { sm = s3; sj = cl0 + 48; }
                const int s = r * 4 + reg;
                if (sm < v1[s]) { v2[s] = v1[s]; pk[s] = (pk[s] << 16) | (unsigned)sj; v1[s] = sm; }
                else if (sm < v2[s]) { v2[s] = sm; pk[s] = (pk[s] & 0xFFFFu) | ((unsigned)sj << 16); }
            }
    };

#define ACC_ZERO() do { \
    _Pragma("unroll") for (int r = 0; r < 2; ++r) \
    _Pragma("unroll") for (int cf = 0; cf < 4; ++cf) acc[r][cf] = (f32x4){0.f,0.f,0.f,0.f}; } while (0)

#define SYNC_V8()  do { asm volatile("s_waitcnt vmcnt(8) lgkmcnt(0)" ::: "memory"); \
    __builtin_amdgcn_sched_barrier(0); __builtin_amdgcn_s_barrier(); } while (0)
#define SYNC_V4()  do { asm volatile("s_waitcnt vmcnt(4) lgkmcnt(0)" ::: "memory"); \
    __builtin_amdgcn_sched_barrier(0); __builtin_amdgcn_s_barrier(); } while (0)
#define SYNC_V0()  do { asm volatile("s_waitcnt vmcnt(0) lgkmcnt(0)" ::: "memory"); \
    __builtin_amdgcn_sched_barrier(0); __builtin_amdgcn_s_barrier(); } while (0)

    // prologue: batches 0,1,2 in flight; wait batch 0 (vmcnt also drains the A-loads above)
    stage(0); stage(1); stage(2);
    asm volatile("s_waitcnt vmcnt(8)" ::: "memory");
    __builtin_amdgcn_sched_barrier(0);
    __builtin_amdgcn_s_barrier();

#pragma unroll 1
    for (int ct = 0; ct < 31; ++ct) {
        ACC_ZERO();
        // prefetch this ct's norms early: their drain coincides with batch s+1's drain
        const int nb = ks * KC + ct * 64 + l15;
        const float nn0 = norms[nb], nn1 = norms[nb + 16];
        const float nn2 = norms[nb + 32], nn3 = norms[nb + 48];
        const int s0 = ct * 4;
#pragma unroll
        for (int dc = 0; dc < 4; ++dc) {
            stage(s0 + dc + 3);
            compute(dc);
            SYNC_V8();
        }
        fold(ct, nn0, nn1, nn2, nn3);
    }
    // ct = 31 tail: steps 124..127
    ACC_ZERO();
    {
        const int nb = ks * KC + 31 * 64 + l15;
        const float nn0 = norms[nb], nn1 = norms[nb + 16];
        const float nn2 = norms[nb + 32], nn3 = norms[nb + 48];
        stage(127); compute(0); SYNC_V8();
        compute(1);             SYNC_V4();
        compute(2);             SYNC_V0();
        compute(3);
        fold(31, nn0, nn1, nn2, nn3);
    }

    // ---- butterfly top2 merge across the 16 column-lanes (l15); l4 preserved ----
#pragma unroll
    for (int m = 1; m < 16; m <<= 1) {
#pragma unroll
        for (int s = 0; s < 8; ++s) {
            float ov1 = __shfl_xor(v1[s], m, 64);
            float ov2 = __shfl_xor(v2[s], m, 64);
            unsigned opk = (unsigned)__shfl_xor((int)pk[s], m, 64);
            const int ia = (int)(pk[s] & 0xFFFFu), ib = (int)(opk & 0xFFFFu);
            bool bl = (ov1 < v1[s]) || (ov1 == v1[s] && ib < ia);
            float f1 = bl ? ov1 : v1[s]; int fi = bl ? ib : ia;
            float rv = bl ? v1[s] : ov1; int ri = bl ? ia : ib;
            float sv = bl ? ov2 : v2[s]; int si = bl ? (int)(opk >> 16) : (int)(pk[s] >> 16);
            bool b2 = (sv < rv) || (sv == rv && si < ri);
            v1[s] = f1; v2[s] = b2 ? sv : rv;
            pk[s] = (unsigned)fi | ((unsigned)(b2 ? si : ri) << 16);
        }
    }
    __syncthreads();   // all compute done; smem safe to reuse
    if (l15 == 0) {
#pragma unroll
        for (int s = 0; s < 8; ++s) {
            const int row = (s >> 2) * 16 + l4 * 4 + (s & 3);
            const int n = w * 32 + row;
            reinterpret_cast<int4*>(smem)[n] =
                make_int4(__float_as_int(v1[s]), (int)(pk[s] & 0xFFFFu),
                          __float_as_int(v2[s]), (int)(pk[s] >> 16));
        }
    }
    __syncthreads();
    if (t < 128) {
        int4 A = reinterpret_cast<int4*>(smem)[t];
        const int n = rb * 128 + t;
        cand_val[n * 8 + ks * 2 + 0] = __int_as_float(A.x);
        cand_val[n * 8 + ks * 2 + 1] = __int_as_float(A.z);
        cand_idx[n * 8 + ks * 2 + 0] = ks * KC + A.y;
        cand_idx[n * 8 + ks * 2 + 1] = ks * KC + A.w;
    }
}

// ---------------- merge splits + exact fp32 rescore of top-2 ----------------
// one wave per row; grid = 4096 blocks of 256. MUST complete before k_finalize
// (k_finalize's z_q writes overwrite the cand_* region carved from d_out).
__global__ void k_merge(const float* __restrict__ z, const float* __restrict__ cb,
                        const float* __restrict__ norms,
                        const float* __restrict__ cand_val, const int* __restrict__ cand_idx,
                        int* __restrict__ fidx) {
    const int gid = blockIdx.x * blockDim.x + threadIdx.x;
    const int wid = gid >> 6;          // row id 0..16383
    const int lane = threadIdx.x & 63;
    float v1 = 3.4e38f, v2 = 3.4e38f; int i1 = 0, i2 = 0;
#pragma unroll
    for (int c = 0; c < 8; ++c) {
        float v = cand_val[wid * 8 + c]; int i = cand_idx[wid * 8 + c] & (KCB - 1);
        bool lt1 = (v < v1) || (v == v1 && i < i1);
        bool lt2 = (v < v2) || (v == v2 && i < i2);
        if (lt1) { v2 = v1; i2 = i1; v1 = v; i1 = i; }
        else if (lt2) { v2 = v; i2 = i; }
    }
    const float4 zq = *reinterpret_cast<const float4*>(z + (size_t)wid * DDIM + lane * 4);
    float d[2]; int ii[2] = { i1, i2 };
#pragma unroll
    for (int c = 0; c < 2; ++c) {
        const float4 e4 = *reinterpret_cast<const float4*>(cb + (size_t)ii[c] * DDIM + lane * 4);
        float s = zq.x * e4.x + zq.y * e4.y + zq.z * e4.z + zq.w * e4.w;
#pragma unroll
        for (int m = 32; m > 0; m >>= 1) s += __shfl_xor(s, m, 64);
        d[c] = norms[ii[c]] - 2.f * s;
    }
    const int best = (d[1] < d[0] || (d[1] == d[0] && ii[1] < ii[0])) ? ii[1] : ii[0];
    if (lane == 0) fidx[wid] = best;
}

// ---------------- copy z_e, gather z_q, loss partials ----------------
__global__ void k_finalize(const float* __restrict__ z, const float* __restrict__ cb,
                           const int* __restrict__ fidx, float* __restrict__ out,
                           float* __restrict__ partials) {
    const int i4 = blockIdx.x * blockDim.x + threadIdx.x;
    float4 zv = *reinterpret_cast<const float4*>(z + (size_t)i4 * 4);
    *reinterpret_cast<float4*>(out + (size_t)i4 * 4) = zv;
    const int n = i4 >> 6;
    const int d0 = (i4 & 63) << 2;
    const int idx = fidx[n] & (KCB - 1);
    float4 q = *reinterpret_cast<const float4*>(cb + (size_t)idx * DDIM + d0);
    float* oq = out + (size_t)ND + 1 + (size_t)i4 * 4;
    oq[0] = q.x; oq[1] = q.y; oq[2] = q.z; oq[3] = q.w;
    const float dx = q.x - zv.x, dy = q.y - zv.y, dz = q.z - zv.z, dw = q.w - zv.w;
    float s = dx * dx + dy * dy + dz * dz + dw * dw;
#pragma unroll
    for (int off = 32; off > 0; off >>= 1) s += __shfl_xor(s, off, 64);
    __shared__ float sm[4];
    const int wv = threadIdx.x >> 6, ln = threadIdx.x & 63;
    if (ln == 0) sm[wv] = s;
    __syncthreads();
    if (threadIdx.x == 0) partials[blockIdx.x] = sm[0] + sm[1] + sm[2] + sm[3];
}

__global__ void k_loss(const float* __restrict__ partials, float* __restrict__ out) {
    float s = 0.f;
    for (int i = threadIdx.x; i < 4096; i += 256) s += partials[i];
#pragma unroll
    for (int off = 32; off > 0; off >>= 1) s += __shfl_xor(s, off, 64);
    __shared__ float sm[4];
    const int wv = threadIdx.x >> 6, ln = threadIdx.x & 63;
    if (ln == 0) sm[wv] = s;
    __syncthreads();
    if (threadIdx.x == 0) out[ND] = 2.0f * (sm[0] + sm[1] + sm[2] + sm[3]) / (float)ND;
}

extern "C" void kernel_launch(void* const* d_in, const int* in_sizes, int n_in,
                              void* d_out, int out_size, void* d_ws, size_t ws_size,
                              hipStream_t stream) {
    const float* z = (const float*)d_in[0];   // [16384, 256]
    const float* cb = (const float*)d_in[1];  // [8192, 256]
    float* out = (float*)d_out;               // z_e[ND], loss[1], z_q[ND]
    float* ws = (float*)d_ws;

    // small scratch in ws (~115 KB)
    float* norms = ws;                        // 8192
    int* fidx = (int*)(ws + 8192);            // 16384
    float* partials = ws + 8192 + 16384;      // 4096

    // big scratch carved from d_out (33.55 MB total; cand_* consumed by k_merge BEFORE
    // k_finalize overwrites d_out with the real outputs)
    char* ob = (char*)d_out;
    unsigned short* zh = (unsigned short*)(ob);                     // 8.39 MB
    unsigned short* zl = (unsigned short*)(ob + 8388608);           // 8.39 MB
    unsigned short* eh = (unsigned short*)(ob + 16777216);          // 4.19 MB
    unsigned short* el = (unsigned short*)(ob + 20971520);          // 4.19 MB
    float* cand_val = (float*)(ob + 25165824);                      // 0.52 MB
    int* cand_idx = (int*)(ob + 25690112);                          // 0.52 MB (ends 26.2 MB < 33.5 MB)

    k_prep<<<dim3(6144), dim3(256), 0, stream>>>(z, cb, zh, zl, eh, el, norms);
    k_score<<<dim3(128, 4), dim3(256), 0, stream>>>(zh, zl, eh, el, norms, cand_val, cand_idx);
    k_merge<<<dim3(4096), dim3(256), 0, stream>>>(z, cb, norms, cand_val, cand_idx, fidx);
    k_finalize<<<dim3(4096), dim3(256), 0, stream>>>(z, cb, fidx, out, partials);
    k_loss<<<dim3(1), dim3(256), 0, stream>>>(partials, out);
}